// Round 1
// baseline (114.014 us; speedup 1.0000x reference)
//
#include <hip/hip_runtime.h>

// PositionalEmbedding: out[node, t*32 + j] = (child_pos(ancestor_t(node)) == j)
// N = 262144 nodes, n = 32 (one-hot width), k = 16 (ancestor depth).
// Output float32 [N, 512] = 512 MiB -> pure HBM-write-bound kernel.

#define NN 32   // one-hot width (n)
#define KK 16   // ancestor depth (k)
#define NPB 256 // nodes per block == threads per block

__global__ __launch_bounds__(256, 8) void pe_kernel(
    const int* __restrict__ parents,
    const int* __restrict__ child_pos,
    float* __restrict__ out, int N)
{
    // codes[node_local][t] : clamped child_pos byte (0xFF => all-zero one-hot)
    __shared__ unsigned char codes[NPB * KK]; // 4 KiB

    const int tid   = threadIdx.x;
    const int node0 = blockIdx.x * NPB;
    const int node  = node0 + tid;

    // ---- Phase A: walk the 16-step ancestor chain, pack 16 code bytes ----
    unsigned int packed[KK / 4];
    if (node < N) {
        int cur = node;
        #pragma unroll
        for (int w = 0; w < KK / 4; ++w) {
            unsigned int u = 0;
            #pragma unroll
            for (int b = 0; b < 4; ++b) {
                int cp = child_pos[cur];            // independent load
                unsigned int byte = (cp < NN) ? (unsigned int)cp : 0xFFu;
                u |= byte << (8 * b);
                cur = parents[cur];                 // dependent chain load
            }
            packed[w] = u;
        }
    } else {
        #pragma unroll
        for (int w = 0; w < KK / 4; ++w) packed[w] = 0xFFFFFFFFu;
    }
    // contiguous ds_write_b128 across lanes (tid*16 bytes) -> conflict-free
    *reinterpret_cast<uint4*>(&codes[tid * KK]) =
        make_uint4(packed[0], packed[1], packed[2], packed[3]);
    __syncthreads();

    // ---- Phase B: cooperative, fully-coalesced one-hot write ----
    // float4 id within block: f = iter*256 + tid
    //   node_local = f >> 7   (128 float4 per node row of 512 floats)
    //   t          = (f >> 3) & 15   == (tid>>3)&15   (iter*32 mod 16 == 0)
    //   quad       = f & 7           == tid & 7
    const int t_seg = (tid >> 3) & 15;
    const int q4    = (tid & 7) * 4;
    const int hi    = tid >> 7; // 0 or 1
    float4* out4 = reinterpret_cast<float4*>(out) + (size_t)node0 * (NN * KK / 4);

    #pragma unroll 4
    for (int iter = 0; iter < (NPB * KK * NN / 4) / 256; ++iter) { // 128 iters
        const int nl   = 2 * iter + hi;
        const int code = codes[nl * KK + t_seg];
        float4 v;
        v.x = (code == q4    ) ? 1.0f : 0.0f;
        v.y = (code == q4 + 1) ? 1.0f : 0.0f;
        v.z = (code == q4 + 2) ? 1.0f : 0.0f;
        v.w = (code == q4 + 3) ? 1.0f : 0.0f;
        if (node0 + nl < N)
            out4[(size_t)iter * 256 + tid] = v;
    }
}

extern "C" void kernel_launch(void* const* d_in, const int* in_sizes, int n_in,
                              void* d_out, int out_size, void* d_ws, size_t ws_size,
                              hipStream_t stream) {
    const int* parents   = (const int*)d_in[0];
    const int* child_pos = (const int*)d_in[1];
    // d_in[2] = n (32), d_in[3] = k (16): fixed by problem, hardcoded above.
    float* out = (float*)d_out;

    const int N    = in_sizes[0] - 1;           // 262144
    const int grid = (N + NPB - 1) / NPB;       // 1024 blocks

    pe_kernel<<<grid, 256, 0, stream>>>(parents, child_pos, out, N);
}